// Round 1
// baseline (2493.557 us; speedup 1.0000x reference)
//
#include <hip/hip_runtime.h>

#define USER_NUM 100000
#define ITEM_NUM 100000
#define NN (USER_NUM + ITEM_NUM)
#define DIM 64
#define EPSV 0.2f

// ---------------------------------------------------------------------------
// concat: ego0 = [user_emb ; item_emb], vectorized float4
// ---------------------------------------------------------------------------
__global__ __launch_bounds__(256) void concat_k(const float* __restrict__ u,
                                                const float* __restrict__ it,
                                                float4* __restrict__ ego) {
    long long idx = (long long)blockIdx.x * blockDim.x + threadIdx.x;
    const long long total = (long long)NN * DIM / 4;
    if (idx >= total) return;
    const long long uelems = (long long)USER_NUM * DIM / 4;
    float4 v = (idx < uelems) ? ((const float4*)u)[idx]
                              : ((const float4*)it)[idx - uelems];
    ego[idx] = v;
}

// ---------------------------------------------------------------------------
// scatter: ego_out[dst] += val * ego_in[src]
// one 64-lane wave per edge, lane = feature dim (coalesced 256B per edge)
// ---------------------------------------------------------------------------
__global__ __launch_bounds__(256) void scatter_k(const int* __restrict__ src,
                                                 const int* __restrict__ dst,
                                                 const float* __restrict__ vals,
                                                 const float* __restrict__ ego_in,
                                                 float* __restrict__ ego_out,
                                                 int E) {
    int e = blockIdx.x * 4 + (threadIdx.x >> 6);
    int lane = threadIdx.x & 63;
    if (e >= E) return;
    int s = src[e];
    int t = dst[e];
    float v = vals[e];
    float x = ego_in[(long long)s * DIM + lane] * v;
    atomicAdd(&ego_out[(long long)t * DIM + lane], x);
}

// ---------------------------------------------------------------------------
// noise injection + accumulate:
//   rn = noise / max(||noise||_2, 1e-12)   (per node, over D)
//   ego += sign(ego) * rn * EPS
//   acc (d_out final half) += ego ; last layer scales by 1/3
//   k==0 also writes cl
// one wave per node; butterfly shfl_xor reduction for the norm
// ---------------------------------------------------------------------------
__global__ __launch_bounds__(256) void noise_k(const float* __restrict__ nz_layer,
                                               float* __restrict__ ego,
                                               float* __restrict__ acc,
                                               float* __restrict__ cl,
                                               int is_first, int is_last,
                                               int write_cl) {
    int node = blockIdx.x * 4 + (threadIdx.x >> 6);
    int lane = threadIdx.x & 63;
    if (node >= NN) return;
    long long off = (long long)node * DIM + lane;
    float nz = nz_layer[off];
    float ss = nz * nz;
    #pragma unroll
    for (int o = 32; o > 0; o >>= 1) ss += __shfl_xor(ss, o, 64);
    float inv = 1.0f / fmaxf(sqrtf(ss), 1e-12f);
    float val = ego[off];
    float sgn = (val > 0.f) ? 1.f : ((val < 0.f) ? -1.f : 0.f);
    val += sgn * nz * inv * EPSV;
    ego[off] = val;  // becomes ego_cur for the next layer
    float a = is_first ? val : (acc[off] + val);
    acc[off] = is_last ? a * (1.0f / 3.0f) : a;
    if (write_cl) cl[off] = val;
}

extern "C" void kernel_launch(void* const* d_in, const int* in_sizes, int n_in,
                              void* d_out, int out_size, void* d_ws, size_t ws_size,
                              hipStream_t stream) {
    const float* user_emb = (const float*)d_in[0];
    const float* item_emb = (const float*)d_in[1];
    const int*   adj_src  = (const int*)d_in[2];
    const int*   adj_dst  = (const int*)d_in[3];
    const float* adj_vals = (const float*)d_in[4];
    const float* noise    = (const float*)d_in[5];
    const int E = in_sizes[2];

    const long long ND = (long long)NN * DIM;
    float* out_final = (float*)d_out;          // [NN, D] -> (final_user, final_item)
    float* out_cl    = out_final + ND;         // [NN, D] -> (cl_user, cl_item)

    float* ego_a = (float*)d_ws;               // ping
    float* ego_b = ego_a + ND;                 // pong

    concat_k<<<(int)((ND / 4 + 255) / 256), 256, 0, stream>>>(user_emb, item_emb,
                                                              (float4*)ego_a);

    float* cur = ego_a;
    float* nxt = ego_b;
    for (int k = 0; k < 3; ++k) {
        hipMemsetAsync(nxt, 0, ND * sizeof(float), stream);
        scatter_k<<<(E + 3) / 4, 256, 0, stream>>>(adj_src, adj_dst, adj_vals,
                                                   cur, nxt, E);
        noise_k<<<(NN + 3) / 4, 256, 0, stream>>>(noise + (long long)k * ND,
                                                  nxt, out_final, out_cl,
                                                  k == 0, k == 2, k == 0);
        float* tmp = cur; cur = nxt; nxt = tmp;
    }
}

// Round 2
// 1164.300 us; speedup vs baseline: 2.1417x; 2.1417x over previous
//
#include <hip/hip_runtime.h>

#define USER_NUM 100000
#define ITEM_NUM 100000
#define NN (USER_NUM + ITEM_NUM)
#define DIM 64
#define EPSV 0.2f

#define SCAN_BLOCK 256
#define SCAN_ITEMS 4
#define SCAN_TILE (SCAN_BLOCK * SCAN_ITEMS)               // 1024
#define SCAN_NBLK ((NN + SCAN_TILE - 1) / SCAN_TILE)      // 196

// ---------------------------------------------------------------------------
// concat: ego0 = [user_emb ; item_emb], vectorized float4
// ---------------------------------------------------------------------------
__global__ __launch_bounds__(256) void concat_k(const float* __restrict__ u,
                                                const float* __restrict__ it,
                                                float4* __restrict__ ego) {
    long long idx = (long long)blockIdx.x * blockDim.x + threadIdx.x;
    const long long total = (long long)NN * DIM / 4;
    if (idx >= total) return;
    const long long uelems = (long long)USER_NUM * DIM / 4;
    float4 v = (idx < uelems) ? ((const float4*)u)[idx]
                              : ((const float4*)it)[idx - uelems];
    ego[idx] = v;
}

// ---------------------------------------------------------------------------
// counting sort by dst: histogram
// ---------------------------------------------------------------------------
__global__ __launch_bounds__(256) void hist_k(const int* __restrict__ dst,
                                              int* __restrict__ hist, int E) {
    int e = blockIdx.x * blockDim.x + threadIdx.x;
    if (e < E) atomicAdd(&hist[dst[e]], 1);
}

// ---------------------------------------------------------------------------
// 3-kernel exclusive scan over NN counters -> row_ptr (and a copy: offsets)
// ---------------------------------------------------------------------------
__global__ __launch_bounds__(SCAN_BLOCK) void scan1_k(const int* __restrict__ in,
                                                      int* __restrict__ outA,
                                                      int* __restrict__ outB,
                                                      int* __restrict__ bsum, int n) {
    __shared__ int tmp[SCAN_BLOCK];
    int t = threadIdx.x;
    int base = blockIdx.x * SCAN_TILE + t * SCAN_ITEMS;
    int v[SCAN_ITEMS];
    int s = 0;
    #pragma unroll
    for (int j = 0; j < SCAN_ITEMS; ++j) {
        int idx = base + j;
        v[j] = (idx < n) ? in[idx] : 0;
        s += v[j];
    }
    tmp[t] = s;
    __syncthreads();
    for (int off = 1; off < SCAN_BLOCK; off <<= 1) {
        int x = (t >= off) ? tmp[t - off] : 0;
        __syncthreads();
        tmp[t] += x;
        __syncthreads();
    }
    int excl = tmp[t] - s;
    if (t == SCAN_BLOCK - 1) bsum[blockIdx.x] = tmp[t];
    int run = excl;
    #pragma unroll
    for (int j = 0; j < SCAN_ITEMS; ++j) {
        int idx = base + j;
        if (idx < n) { outA[idx] = run; outB[idx] = run; }
        run += v[j];
    }
}

__global__ __launch_bounds__(256) void scan2_k(int* __restrict__ bsum, int nb) {
    __shared__ int tmp[256];
    int t = threadIdx.x;
    int s = (t < nb) ? bsum[t] : 0;
    tmp[t] = s;
    __syncthreads();
    for (int off = 1; off < 256; off <<= 1) {
        int x = (t >= off) ? tmp[t - off] : 0;
        __syncthreads();
        tmp[t] += x;
        __syncthreads();
    }
    if (t < nb) bsum[t] = tmp[t] - s;
}

__global__ __launch_bounds__(256) void scan3_k(int* __restrict__ outA,
                                               int* __restrict__ outB,
                                               const int* __restrict__ bsum,
                                               int n, int E) {
    int idx = blockIdx.x * blockDim.x + threadIdx.x;
    if (idx < n) {
        int add = bsum[idx / SCAN_TILE];
        outA[idx] += add;
        outB[idx] += add;
    }
    if (idx == 0) outA[n] = E;   // row_ptr[NN] = E
}

// ---------------------------------------------------------------------------
// place edges into dst-sorted order as packed (src, val) int2 records
// ---------------------------------------------------------------------------
__global__ __launch_bounds__(256) void place_k(const int* __restrict__ src,
                                               const int* __restrict__ dst,
                                               const float* __restrict__ vals,
                                               int* __restrict__ offsets,
                                               int2* __restrict__ ssv, int E) {
    int e = blockIdx.x * blockDim.x + threadIdx.x;
    if (e >= E) return;
    int d = dst[e];
    int pos = atomicAdd(&offsets[d], 1);
    ssv[pos] = make_int2(src[e], __float_as_int(vals[e]));
}

// ---------------------------------------------------------------------------
// fused segmented SpMM + noise injection + acc (+cl via ego_out on layer 1)
// one 64-lane wave per dst row; lane = feature dim.
// Edge records broadcast via v_readlane (wave-uniform loop index).
// ---------------------------------------------------------------------------
__global__ __launch_bounds__(256) void spmm_fused_k(const int* __restrict__ row_ptr,
                                                    const int2* __restrict__ ssv,
                                                    const float* __restrict__ ego_in,
                                                    float* __restrict__ ego_out,
                                                    const float* __restrict__ nz_layer,
                                                    float* __restrict__ acc,
                                                    int is_first, int is_last) {
    int node = blockIdx.x * 4 + (threadIdx.x >> 6);   // grid sized so node < NN
    int lane = threadIdx.x & 63;
    int beg = row_ptr[node];
    int end = row_ptr[node + 1];

    float a = 0.f;
    int base = beg;
    // full chunks of 16 edges: lanes 0..15 hold the records, broadcast j=0..15
    for (; base + 16 <= end; base += 16) {
        int2 sv = ssv[base + (lane & 15)];
        #pragma unroll
        for (int j = 0; j < 16; ++j) {
            int sj = __builtin_amdgcn_readlane(sv.x, j);
            float vj = __int_as_float(__builtin_amdgcn_readlane(sv.y, j));
            a += ego_in[(long long)sj * DIM + lane] * vj;
        }
    }
    // tail (< 16 edges), clamped load to stay in-bounds
    int rem = end - base;
    if (rem > 0) {
        int i = base + (lane & 15);
        if (i >= end) i = end - 1;
        int2 sv = ssv[i];
        for (int j = 0; j < rem; ++j) {
            int sj = __builtin_amdgcn_readlane(sv.x, j);
            float vj = __int_as_float(__builtin_amdgcn_readlane(sv.y, j));
            a += ego_in[(long long)sj * DIM + lane] * vj;
        }
    }

    // epilogue: noise injection + acc (+ ego write unless last layer)
    long long off = (long long)node * DIM + lane;
    float nz = nz_layer[off];
    float ss = nz * nz;
    #pragma unroll
    for (int o = 32; o > 0; o >>= 1) ss += __shfl_xor(ss, o, 64);
    float inv = 1.0f / fmaxf(sqrtf(ss), 1e-12f);
    float sgn = (a > 0.f) ? 1.f : ((a < 0.f) ? -1.f : 0.f);
    float val = a + sgn * nz * inv * EPSV;
    if (!is_last) ego_out[off] = val;     // layer1: ego_out == out_cl (doubles as cl)
    float r = is_first ? val : (acc[off] + val);
    acc[off] = is_last ? r * (1.0f / 3.0f) : r;
}

extern "C" void kernel_launch(void* const* d_in, const int* in_sizes, int n_in,
                              void* d_out, int out_size, void* d_ws, size_t ws_size,
                              hipStream_t stream) {
    const float* user_emb = (const float*)d_in[0];
    const float* item_emb = (const float*)d_in[1];
    const int*   adj_src  = (const int*)d_in[2];
    const int*   adj_dst  = (const int*)d_in[3];
    const float* adj_vals = (const float*)d_in[4];
    const float* noise    = (const float*)d_in[5];
    const int E = in_sizes[2];

    const long long ND = (long long)NN * DIM;
    float* out_final = (float*)d_out;      // [NN, D] final
    float* out_cl    = out_final + ND;     // [NN, D] cl  (also ego buffer for layer 1)

    // workspace layout (~78 MB)
    float* ego_a   = (float*)d_ws;                 // ND floats
    int2*  ssv     = (int2*)(ego_a + ND);          // E records (8 B each)
    int*   hist    = (int*)(ssv + E);              // NN
    int*   row_ptr = hist + NN;                    // NN + 1
    int*   offsets = row_ptr + NN + 1;             // NN
    int*   bsum    = offsets + NN;                 // SCAN_NBLK

    concat_k<<<(int)((ND / 4 + 255) / 256), 256, 0, stream>>>(user_emb, item_emb,
                                                              (float4*)ego_a);

    // --- build CSR (counting sort by dst) ---
    hipMemsetAsync(hist, 0, (size_t)NN * sizeof(int), stream);
    hist_k<<<(E + 255) / 256, 256, 0, stream>>>(adj_dst, hist, E);
    scan1_k<<<SCAN_NBLK, SCAN_BLOCK, 0, stream>>>(hist, row_ptr, offsets, bsum, NN);
    scan2_k<<<1, 256, 0, stream>>>(bsum, SCAN_NBLK);
    scan3_k<<<(NN + 255) / 256, 256, 0, stream>>>(row_ptr, offsets, bsum, NN, E);
    place_k<<<(E + 255) / 256, 256, 0, stream>>>(adj_src, adj_dst, adj_vals,
                                                 offsets, ssv, E);

    // --- 3 fused layers ---
    const int spmm_grid = NN / 4;   // 200000 waves exactly
    // layer 1: ego0(ego_a) -> out_cl (== cl), acc = val
    spmm_fused_k<<<spmm_grid, 256, 0, stream>>>(row_ptr, ssv, ego_a, out_cl,
                                                noise, out_final, 1, 0);
    // layer 2: out_cl -> ego_a, acc += val
    spmm_fused_k<<<spmm_grid, 256, 0, stream>>>(row_ptr, ssv, out_cl, ego_a,
                                                noise + ND, out_final, 0, 0);
    // layer 3: ego_a -> (no ego write), acc = (acc + val)/3
    spmm_fused_k<<<spmm_grid, 256, 0, stream>>>(row_ptr, ssv, ego_a, nullptr,
                                                noise + 2 * ND, out_final, 0, 1);
}

// Round 3
// 891.616 us; speedup vs baseline: 2.7967x; 1.3058x over previous
//
#include <hip/hip_runtime.h>

#define USER_NUM 100000
#define ITEM_NUM 100000
#define NN 200000
#define DIM 64
#define EPSV 0.2f

#define NB 196          // coarse buckets of 1024 dst-nodes (ceil(200000/1024))
#define BSH 10          // bucket = dst >> 10
#define NPB 1024        // nodes per bucket
#define CH 4096         // edges per workgroup chunk in pass A
#define PER 16          // edges per thread (256*16 = 4096)
#define SRC_MASK 0x3FFFF

// ---------------------------------------------------------------------------
// K1: coarse bucket histogram (196 counters) via LDS aggregation
// ---------------------------------------------------------------------------
__global__ __launch_bounds__(256) void bhist_k(const int* __restrict__ dst,
                                               int* __restrict__ bhist, int E) {
    __shared__ int h[NB];
    int t = threadIdx.x;
    for (int i = t; i < NB; i += 256) h[i] = 0;
    __syncthreads();
    long long base = (long long)blockIdx.x * CH;
    #pragma unroll
    for (int j = 0; j < PER; ++j) {
        long long e = base + t + j * 256;
        if (e < E) atomicAdd(&h[dst[e] >> BSH], 1);
    }
    __syncthreads();
    for (int i = t; i < NB; i += 256) if (h[i]) atomicAdd(&bhist[i], h[i]);
}

// ---------------------------------------------------------------------------
// K2: exclusive scan over 196 bucket counts (single block)
// ---------------------------------------------------------------------------
__global__ __launch_bounds__(256) void bscan_k(const int* __restrict__ bhist,
                                               int* __restrict__ bucket_base,
                                               int* __restrict__ bucket_off,
                                               int* __restrict__ row_ptr, int E) {
    __shared__ int tmp[256];
    int t = threadIdx.x;
    int s = (t < NB) ? bhist[t] : 0;
    tmp[t] = s;
    __syncthreads();
    for (int off = 1; off < 256; off <<= 1) {
        int x = (t >= off) ? tmp[t - off] : 0;
        __syncthreads();
        tmp[t] += x;
        __syncthreads();
    }
    int excl = tmp[t] - s;
    if (t < NB) { bucket_base[t] = excl; bucket_off[t] = excl; }
    if (t == 0) { bucket_base[NB] = E; row_ptr[NN] = E; }
}

// ---------------------------------------------------------------------------
// K3 (pass A): LDS multi-split into 196 bucket regions, dense run writes.
// Record: x = src | (dst&1023)<<18 ; y = val bits.
// ---------------------------------------------------------------------------
__global__ __launch_bounds__(256) void apart_k(const int* __restrict__ src,
                                               const int* __restrict__ dst,
                                               const float* __restrict__ vals,
                                               int* __restrict__ bucket_off,
                                               int2* __restrict__ out, int E) {
    __shared__ int cnt[NB], start[NB], cursor[NB], gbase[NB];
    __shared__ int tmp[256];
    __shared__ int2 rec[CH];
    int t = threadIdx.x;
    long long base = (long long)blockIdx.x * CH;
    int nvalid = (int)min((long long)CH, (long long)E - base);

    int s_[PER]; int d_[PER]; float v_[PER];
    for (int i = t; i < NB; i += 256) cnt[i] = 0;
    __syncthreads();
    #pragma unroll
    for (int j = 0; j < PER; ++j) {
        int idx = t + j * 256;
        if (idx < nvalid) {
            long long e = base + idx;
            d_[j] = dst[e]; s_[j] = src[e]; v_[j] = vals[e];
            atomicAdd(&cnt[d_[j] >> BSH], 1);
        } else d_[j] = -1;
    }
    __syncthreads();
    int c = (t < NB) ? cnt[t] : 0;
    tmp[t] = c;
    __syncthreads();
    for (int off = 1; off < 256; off <<= 1) {
        int x = (t >= off) ? tmp[t - off] : 0;
        __syncthreads();
        tmp[t] += x;
        __syncthreads();
    }
    if (t < NB) {
        int excl = tmp[t] - c;
        start[t] = excl; cursor[t] = excl;
        gbase[t] = (c > 0) ? atomicAdd(&bucket_off[t], c) : 0;
    }
    __syncthreads();
    #pragma unroll
    for (int j = 0; j < PER; ++j) {
        if (d_[j] >= 0) {
            int b = d_[j] >> BSH;
            int slot = atomicAdd(&cursor[b], 1);
            rec[slot] = make_int2(s_[j] | ((d_[j] & (NPB - 1)) << 18),
                                  __float_as_int(v_[j]));
        }
    }
    __syncthreads();
    // flush: consecutive LDS slots -> contiguous global runs per bucket
    for (int slot = t; slot < nvalid; slot += 256) {
        int lo = 0, hi = NB - 1;
        while (lo < hi) {
            int mid = (lo + hi + 1) >> 1;
            if (start[mid] <= slot) lo = mid; else hi = mid - 1;
        }
        out[gbase[lo] + (slot - start[lo])] = rec[slot];
    }
}

// ---------------------------------------------------------------------------
// K4 (pass B): one WG per bucket. Per-node hist + scan in LDS -> row_ptr,
// then scatter to final CSR position (random only within ~130KB, 1 CU).
// ---------------------------------------------------------------------------
__global__ __launch_bounds__(256) void bsort_k(const int* __restrict__ bucket_base,
                                               const int2* __restrict__ in,
                                               int2* __restrict__ out,
                                               int* __restrict__ row_ptr) {
    __shared__ int noff[NPB];
    __shared__ int tmp[256];
    int b = blockIdx.x, t = threadIdx.x;
    int rbeg = bucket_base[b], rend = bucket_base[b + 1];
    for (int i = t; i < NPB; i += 256) noff[i] = 0;
    __syncthreads();
    for (int i = rbeg + t; i < rend; i += 256)
        atomicAdd(&noff[(in[i].x >> 18) & (NPB - 1)], 1);
    __syncthreads();
    // exclusive scan of 1024 counters with 256 threads (4 each)
    int l0 = noff[t * 4], l1 = noff[t * 4 + 1], l2 = noff[t * 4 + 2], l3 = noff[t * 4 + 3];
    int s = l0 + l1 + l2 + l3;
    tmp[t] = s;
    __syncthreads();
    for (int off = 1; off < 256; off <<= 1) {
        int x = (t >= off) ? tmp[t - off] : 0;
        __syncthreads();
        tmp[t] += x;
        __syncthreads();
    }
    int run = rbeg + tmp[t] - s;
    int e0 = run, e1 = run + l0, e2 = e1 + l1, e3 = e2 + l2;
    noff[t * 4] = e0; noff[t * 4 + 1] = e1; noff[t * 4 + 2] = e2; noff[t * 4 + 3] = e3;
    int node0 = b * NPB + t * 4;
    if (node0 < NN)     row_ptr[node0]     = e0;
    if (node0 + 1 < NN) row_ptr[node0 + 1] = e1;
    if (node0 + 2 < NN) row_ptr[node0 + 2] = e2;
    if (node0 + 3 < NN) row_ptr[node0 + 3] = e3;
    __syncthreads();
    for (int i = rbeg + t; i < rend; i += 256) {
        int2 r = in[i];
        int pos = atomicAdd(&noff[(r.x >> 18) & (NPB - 1)], 1);
        out[pos] = r;
    }
}

// ---------------------------------------------------------------------------
// fused segmented SpMM + noise injection + acc.
// one 64-lane wave per dst row; lane = feature dim; records broadcast via
// readlane. Layer 1 reads the concat virtually via dual base pointers.
// ---------------------------------------------------------------------------
__global__ __launch_bounds__(256) void spmm_fused_k(const int* __restrict__ row_ptr,
                                                    const int2* __restrict__ ssv,
                                                    const float* __restrict__ ego_u,
                                                    const float* __restrict__ ego_i,
                                                    float* __restrict__ ego_out,
                                                    const float* __restrict__ nz_layer,
                                                    float* __restrict__ acc,
                                                    int is_first, int is_last) {
    int node = blockIdx.x * 4 + (threadIdx.x >> 6);
    int lane = threadIdx.x & 63;
    int beg = row_ptr[node];
    int end = row_ptr[node + 1];

    float a = 0.f;
    int base = beg;
    for (; base + 16 <= end; base += 16) {
        int2 sv = ssv[base + (lane & 15)];
        #pragma unroll
        for (int j = 0; j < 16; ++j) {
            int sj = __builtin_amdgcn_readlane(sv.x, j) & SRC_MASK;
            float vj = __int_as_float(__builtin_amdgcn_readlane(sv.y, j));
            const float* eb = (sj < USER_NUM) ? ego_u : ego_i;
            a += eb[(long long)sj * DIM + lane] * vj;
        }
    }
    int rem = end - base;
    if (rem > 0) {
        int i = base + (lane & 15);
        if (i >= end) i = end - 1;
        int2 sv = ssv[i];
        for (int j = 0; j < rem; ++j) {
            int sj = __builtin_amdgcn_readlane(sv.x, j) & SRC_MASK;
            float vj = __int_as_float(__builtin_amdgcn_readlane(sv.y, j));
            const float* eb = (sj < USER_NUM) ? ego_u : ego_i;
            a += eb[(long long)sj * DIM + lane] * vj;
        }
    }

    long long off = (long long)node * DIM + lane;
    float nz = nz_layer[off];
    float ss = nz * nz;
    #pragma unroll
    for (int o = 32; o > 0; o >>= 1) ss += __shfl_xor(ss, o, 64);
    float inv = 1.0f / fmaxf(sqrtf(ss), 1e-12f);
    float sgn = (a > 0.f) ? 1.f : ((a < 0.f) ? -1.f : 0.f);
    float val = a + sgn * nz * inv * EPSV;
    if (!is_last) ego_out[off] = val;
    float r = is_first ? val : (acc[off] + val);
    acc[off] = is_last ? r * (1.0f / 3.0f) : r;
}

extern "C" void kernel_launch(void* const* d_in, const int* in_sizes, int n_in,
                              void* d_out, int out_size, void* d_ws, size_t ws_size,
                              hipStream_t stream) {
    const float* user_emb = (const float*)d_in[0];
    const float* item_emb = (const float*)d_in[1];
    const int*   adj_src  = (const int*)d_in[2];
    const int*   adj_dst  = (const int*)d_in[3];
    const float* adj_vals = (const float*)d_in[4];
    const float* noise    = (const float*)d_in[5];
    const int E = in_sizes[2];

    const long long ND = (long long)NN * DIM;
    float* out_final = (float*)d_out;       // [NN, D] final
    float* out_cl    = out_final + ND;      // [NN, D] cl (also ego after layer 1)

    // workspace layout (~78 MB). ego_a aliases the pass-A bucketed records:
    // ssv_b is dead after bsort_k, before ego_a's first write (layer-2 spmm).
    char*  w       = (char*)d_ws;
    float* ego_a   = (float*)w;                          // ND floats (51.2 MB)
    int2*  ssv_b   = (int2*)w;                           // E records (25.6 MB), aliased
    int2*  ssv     = (int2*)(w + ND * sizeof(float));    // E records (25.6 MB)
    int*   bhist   = (int*)(ssv + E);                    // NB
    int*   bbase   = bhist + NB;                         // NB + 1
    int*   boff    = bbase + NB + 1;                     // NB
    int*   row_ptr = boff + NB;                          // NN + 1

    const int nchunk = (E + CH - 1) / CH;

    hipMemsetAsync(bhist, 0, NB * sizeof(int), stream);
    bhist_k<<<nchunk, 256, 0, stream>>>(adj_dst, bhist, E);
    bscan_k<<<1, 256, 0, stream>>>(bhist, bbase, boff, row_ptr, E);
    apart_k<<<nchunk, 256, 0, stream>>>(adj_src, adj_dst, adj_vals, boff, ssv_b, E);
    bsort_k<<<NB, 256, 0, stream>>>(bbase, ssv_b, ssv, row_ptr);

    const int spmm_grid = NN / 4;   // 200000 waves
    const float* item_shift = item_emb - (long long)USER_NUM * DIM;
    // layer 1: virtual concat(user,item) -> out_cl (doubles as cl), acc = val
    spmm_fused_k<<<spmm_grid, 256, 0, stream>>>(row_ptr, ssv, user_emb, item_shift,
                                                out_cl, noise, out_final, 1, 0);
    // layer 2: out_cl -> ego_a, acc += val
    spmm_fused_k<<<spmm_grid, 256, 0, stream>>>(row_ptr, ssv, out_cl, out_cl,
                                                ego_a, noise + ND, out_final, 0, 0);
    // layer 3: ego_a -> (no ego write), acc = (acc + val)/3
    spmm_fused_k<<<spmm_grid, 256, 0, stream>>>(row_ptr, ssv, ego_a, ego_a,
                                                nullptr, noise + 2 * ND, out_final, 0, 1);
}